// Round 7
// baseline (5590.060 us; speedup 1.0000x reference)
//
#include <hip/hip_runtime.h>
#include <hip/hip_bf16.h>

#define TT 512
#define BB 256
#define II 13
#define HH 512
#define KP 544              // logical K: [0,512)=h, [512,525)=x, 525=1.0 (bias), rest 0
#define KPL 552             // LDS W row stride (bank spread)
#define NBLK 256
#define NTH 256
#define PS (BB * KP)        // elems per (buf,plane): 139264
#define NKT 17              // K tiles of 32
#define GST 18              // pbuf row stride (floats)
#define PBS (4 * 32 * GST)  // one partial buffer: 2304 floats
#define XROW (BB * II)      // 3328

typedef __attribute__((ext_vector_type(8))) short short8;
typedef __attribute__((ext_vector_type(4))) float floatx4;
typedef __attribute__((ext_vector_type(4))) int intx4;

__device__ inline float sigm(float v) { return 1.f / (1.f + __expf(-v)); }
__device__ inline float tanh_(float v) {
    float e = __expf(-2.f * fabsf(v));
    float t = (1.f - e) / (1.f + e);
    return v < 0.f ? -t : t;
}
__device__ inline void split_bits(float v, unsigned short* hi, unsigned short* lo) {
    __hip_bfloat16 h = __float2bfloat16(v);
    float r = v - __bfloat162float(h);
    __hip_bfloat16 l = __float2bfloat16(r);
    *hi = __builtin_bit_cast(unsigned short, h);
    *lo = __builtin_bit_cast(unsigned short, l);
}

// ---- MALL-direct (uncached) access path: sc0 sc1 bypasses vL1 AND L2.
// Empirically validated R4/R5. All cross-block data (hbuf) travels it.
__device__ inline unsigned poll_mall(const unsigned* p) {
    unsigned v;
    asm volatile("global_load_dword %0, %1, off sc0 sc1\n\ts_waitcnt vmcnt(0)"
                 : "=v"(v) : "v"(p) : "memory");
    return v;
}
__device__ inline void arrive_mall(unsigned* p) {
    asm volatile("global_atomic_add %0, %1, off sc1" :: "v"(p), "v"(1u) : "memory");
}
__device__ inline intx4 load_b128_uc(const void* p) {   // issue only; NO waitcnt
    intx4 v;
    asm volatile("global_load_dwordx4 %0, %1, off sc0 sc1" : "=v"(v) : "v"(p));
    return v;
}
__device__ inline void store_short_uc(void* p, unsigned short v) {
    unsigned vv = v;
    asm volatile("global_store_short %0, %1, off sc0 sc1" :: "v"(p), "v"(vv) : "memory");
}
__device__ inline void store_dword_uc(void* p, unsigned v) {
    asm volatile("global_store_dword %0, %1, off sc0 sc1" :: "v"(p), "v"(v) : "memory");
}
__device__ inline void store_f32_wt(float* p, float v) {
    asm volatile("global_store_dword %0, %1, off sc0 sc1" :: "v"(p), "v"(v) : "memory");
}

// In-XCD barrier, counter at MALL (see R4/R5 notes). __syncthreads drains each
// wave's vmcnt -> all sc0sc1 stores at MALL before tid0's arrive. Bounded spin.
__device__ inline void barrier_xcd(unsigned* cnt, unsigned target) {
    __syncthreads();
    if (threadIdx.x == 0) {
        arrive_mall(cnt);
        int guard = 0;
        unsigned v;
        do { v = poll_mall(cnt); } while ((int)(v - target) < 0 && ++guard < (1 << 16));
    }
    __syncthreads();
}

// Per-wave K-segment GEMM partial: tiles [KS,KE) of A (both batch halves, both
// planes, MALL-direct) x W (LDS) -> acc[2 batch-halves][4 gates]. Compile-time
// bounds keep all frag arrays in registers (rule #20).
// Wh/Wl are PRE-OFFSET by browBase + kgo (R6 bug: kgo was dropped from the
// B-loads -> lanes 16-63 read k-chunk 0's W elements; fixed by baking it in).
template<int KS, int KE>
__device__ __forceinline__ void kbody(const short* A00, const short* A01,
                                      const short* A10, const short* A11,
                                      const __hip_bfloat16* Wh,
                                      const __hip_bfloat16* Wl,
                                      floatx4 (&acc)[2][4])
{
    constexpr int NT = KE - KS;
    intx4 ah[2][NT], al[2][NT];
#pragma unroll
    for (int j = 0; j < NT; ++j) {
        ah[0][j] = load_b128_uc(A00 + (KS + j) * 32);
        ah[1][j] = load_b128_uc(A01 + (KS + j) * 32);
        al[0][j] = load_b128_uc(A10 + (KS + j) * 32);
        al[1][j] = load_b128_uc(A11 + (KS + j) * 32);
    }
    asm volatile("s_waitcnt vmcnt(0)" ::: "memory");
    __builtin_amdgcn_sched_barrier(0);   // rule #18: keep MFMAs below the drain
#pragma unroll
    for (int j = 0; j < NT; ++j) {
        const int k0 = (KS + j) * 32;
        short8 bh[4], bv[4];
#pragma unroll
        for (int g = 0; g < 4; ++g) {
            const int bo = g * 16 * KPL + k0;
            bh[g] = *(const short8*)(Wh + bo);
            bv[g] = *(const short8*)(Wl + bo);
        }
        // product-major order: reuse distance 8 on each acc (no dep stalls)
#pragma unroll
        for (int p = 0; p < 3; ++p) {
#pragma unroll
            for (int m = 0; m < 2; ++m) {
                short8 av = __builtin_bit_cast(short8, (p == 2) ? al[m][j] : ah[m][j]);
#pragma unroll
                for (int g = 0; g < 4; ++g)
                    acc[m][g] = __builtin_amdgcn_mfma_f32_16x16x32_bf16(
                        av, (p == 1) ? bv[g] : bh[g], acc[m][g], 0, 0, 0);
            }
        }
    }
}

__global__ void __launch_bounds__(NTH, 1)
lstm_persist(const float* __restrict__ X,   const float* __restrict__ Wih,
             const float* __restrict__ Whh, const float* __restrict__ bih,
             const float* __restrict__ bhh, const float* __restrict__ Wout,
             const float* __restrict__ bout, float* __restrict__ Y,
             __hip_bfloat16* __restrict__ hbuf, unsigned* __restrict__ bars)
{
    extern __shared__ char smem[];
    __hip_bfloat16* Wshi = (__hip_bfloat16*)smem;       // [64][KPL] hi
    __hip_bfloat16* Wslo = Wshi + 64 * KPL;             // [64][KPL] lo
    float* pbuf = (float*)(Wslo + 64 * KPL);            // [2][4][32][GST] partials
    int* shint = (int*)(pbuf + 2 * PBS);

    const int tid = threadIdx.x;

    // ---- runtime role assignment: bc = physical XCD, hs = rank within XCD.
    // ~156KB LDS forces 1 block/CU; 256 blocks on 256 CUs => exactly 32/XCD.
    if (tid == 0) {
        unsigned x = __builtin_amdgcn_s_getreg(20 | (3 << 11)) & 7u; // HW_REG_XCC_ID
        unsigned r = __hip_atomic_fetch_add(bars + 256 + x * 16, 1u,
                        __ATOMIC_RELAXED, __HIP_MEMORY_SCOPE_AGENT);
        shint[0] = (int)x;
        shint[1] = (int)(r & 31u);
    }
    __syncthreads();
    const int bc = shint[0];
    const int hs = shint[1];
    unsigned* bcnt = bars + bc * 32;

    // ---- init: OWN-ROW ONLY, all hbuf writes uncached (MALL-direct) ----
    {
        const int row = bc * 32 + hs;
        unsigned* hb32 = (unsigned*)hbuf;
        const int rw = row * (KP / 2);
        for (int i = tid; i < KP / 2; i += NTH) {    // zero 4 (buf,plane) images
            store_dword_uc(hb32 +               rw + i, 0u);
            store_dword_uc(hb32 + (PS / 2)    + rw + i, 0u);
            store_dword_uc(hb32 + PS          + rw + i, 0u);
            store_dword_uc(hb32 + PS + PS / 2 + rw + i, 0u);
        }
        const float b0 = bout[0];
        for (int i = tid; i < 16 * 32; i += NTH) {   // Y[hs*16..+16)[bc*32..+32)
            int tr = hs * 16 + (i >> 5), cb = bc * 32 + (i & 31);
            store_f32_wt(&Y[tr * BB + cb], b0);
        }
        __syncthreads();   // own-row zeroing done before bias/x writes
        if (tid == 0) {    // bias-one column, both buffers (bf16 1.0 = 0x3F80)
            store_short_uc(hbuf +          row * KP + (HH + II), 0x3F80u);
            store_short_uc(hbuf + 2 * PS + row * KP + (HH + II), 0x3F80u);
        }
        if (tid < II) {    // x_0 for own row, both planes
            unsigned short hi, lo; split_bits(X[row * II + tid], &hi, &lo);
            store_short_uc(hbuf +      row * KP + HH + tid, hi);
            store_short_uc(hbuf + PS + row * KP + HH + tid, lo);
        }
    }
    // ---- W slice -> LDS (hi/lo split), padded stride ----
    for (int n = 0; n < 64; ++n) {
        int gate = n >> 4, hl = n & 15;
        int gr = gate * HH + hs * 16 + hl;   // global gate row (i,f,g,o order)
        for (int k = tid; k < KP; k += NTH) {
            float v;
            if (k < HH)            v = Whh[gr * HH + k];
            else if (k < HH + II)  v = Wih[gr * II + (k - HH)];
            else if (k == HH + II) v = bih[gr] + bhh[gr];
            else                   v = 0.f;
            unsigned short hi, lo; split_bits(v, &hi, &lo);
            Wshi[n * KPL + k] = __builtin_bit_cast(__hip_bfloat16, hi);
            Wslo[n * KPL + k] = __builtin_bit_cast(__hip_bfloat16, lo);
        }
    }
    // ---- x_1 register preload (hs==1 stages x_1 at t=0) ----
    const int e0 = 2 * tid;
    const bool stv = (e0 < 32 * II);
    const int bl0 = e0 / II, xc0 = e0 - bl0 * II;
    const int e1 = e0 + 1;
    const int bl1 = e1 / II, xc1 = e1 - bl1 * II;
    float xr0 = 0.f, xr1 = 0.f;
    if (hs == 1 && stv) {
        const float2 v = *(const float2*)(X + XROW + bc * (32 * II) + e0);
        xr0 = v.x; xr1 = v.y;
    }

    barrier_xcd(bcnt, 32u);   // init done (epoch 1)

    // ---- main recurrence ----
    const int lane = tid & 63, wid = tid >> 6;
    const int r15  = lane & 15;
    const int kgo  = (lane >> 4) * 8;
    const int qr   = (lane >> 4) * 4;       // D-frag row base within 16
    float c0 = 0.f, c1 = 0.f;
    const int ebl = tid >> 4;               // elementwise (b_loc, h) mapping
    const int eh  = tid & 15;
    const float wout = Wout[hs * 16 + eh];
    float* pbw = pbuf + (wid & 1) * PBS;    // waves 0/2 -> pbuf0, 1/3 -> pbuf1
    const __hip_bfloat16* Wh = Wshi + r15 * KPL + kgo;   // browBase + kgo baked in
    const __hip_bfloat16* Wl = Wslo + r15 * KPL + kgo;

    for (int t = 0; t < TT; ++t) {
        const int cur = t & 1, nxt = cur ^ 1;
        const short* base = (const short*)hbuf + cur * 2 * PS;
        const short* A00 = base + (bc * 32 + r15) * KP + kgo;   // hi, batch 0-15
        const short* A01 = A00 + 16 * KP;                        // hi, batch 16-31
        const short* A10 = A00 + PS;                             // lo, batch 0-15
        const short* A11 = A01 + PS;                             // lo, batch 16-31

        floatx4 acc[2][4];
#pragma unroll
        for (int m = 0; m < 2; ++m)
#pragma unroll
            for (int g = 0; g < 4; ++g)
                acc[m][g] = floatx4{0.f, 0.f, 0.f, 0.f};

        switch (wid) {   // wave-uniform branch; compile-time K-bounds
            case 0:  kbody<0, 5>  (A00, A01, A10, A11, Wh, Wl, acc); break;
            case 1:  kbody<5, 9>  (A00, A01, A10, A11, Wh, Wl, acc); break;
            case 2:  kbody<9, 13> (A00, A01, A10, A11, Wh, Wl, acc); break;
            default: kbody<13, 17>(A00, A01, A10, A11, Wh, Wl, acc); break;
        }

        // ---- cross-wave K-reduction through LDS: waves 0,1 store; 2,3 add ----
        if (wid < 2) {
#pragma unroll
            for (int m = 0; m < 2; ++m)
#pragma unroll
                for (int g = 0; g < 4; ++g)
#pragma unroll
                    for (int r = 0; r < 4; ++r)
                        pbw[(g * 32 + m * 16 + qr + r) * GST + r15] = acc[m][g][r];
        }
        __syncthreads();
        if (wid >= 2) {
#pragma unroll
            for (int m = 0; m < 2; ++m)
#pragma unroll
                for (int g = 0; g < 4; ++g)
#pragma unroll
                    for (int r = 0; r < 4; ++r)
                        atomicAdd(&pbw[(g * 32 + m * 16 + qr + r) * GST + r15],
                                  acc[m][g][r]);
        }
        __syncthreads();

        __hip_bfloat16* hb = hbuf + nxt * 2 * PS;
        {   // elementwise: this thread owns (ebl, eh) and (ebl+16, eh)
            float* pb0 = pbuf;
            float* pb1 = pbuf + PBS;
#define GV(g, bb) (pb0[((g) * 32 + (bb)) * GST + eh] + pb1[((g) * 32 + (bb)) * GST + eh])
            float gi0 = GV(0, ebl),      gf0 = GV(1, ebl);
            float gg0 = GV(2, ebl),      go0 = GV(3, ebl);
            float gi1 = GV(0, ebl + 16), gf1 = GV(1, ebl + 16);
            float gg1 = GV(2, ebl + 16), go1 = GV(3, ebl + 16);
#undef GV
            c0 = sigm(gf0) * c0 + sigm(gi0) * tanh_(gg0);
            float h0 = sigm(go0) * tanh_(c0);
            c1 = sigm(gf1) * c1 + sigm(gi1) * tanh_(gg1);
            float h1 = sigm(go1) * tanh_(c1);

            int b = bc * 32 + ebl;
            int kcol = hs * 16 + eh;
            unsigned short hi, lo;
            split_bits(h0, &hi, &lo);
            store_short_uc(hb +      b * KP + kcol, hi);
            store_short_uc(hb + PS + b * KP + kcol, lo);
            split_bits(h1, &hi, &lo);
            store_short_uc(hb +      (b + 16) * KP + kcol, hi);
            store_short_uc(hb + PS + (b + 16) * KP + kcol, lo);

            float p0 = fmaxf(h0, 0.f) * wout;
            float p1 = fmaxf(h1, 0.f) * wout;
#pragma unroll
            for (int s = 8; s >= 1; s >>= 1) {
                p0 += __shfl_xor(p0, s);
                p1 += __shfl_xor(p1, s);
            }
            if (eh == 0) {
                atomicAdd(&Y[t * BB + b], p0);
                atomicAdd(&Y[t * BB + b + 16], p1);
            }
        }
        // rotating x-stager: owner of time s stages at t=s-1 from regs
        // preloaded at t=s-2 (HBM latency hidden under a full step)
        if (t + 1 < TT && hs == ((t + 1) & 31) && stv) {
            unsigned short hi, lo;
            split_bits(xr0, &hi, &lo);
            store_short_uc(hb +      (bc * 32 + bl0) * KP + HH + xc0, hi);
            store_short_uc(hb + PS + (bc * 32 + bl0) * KP + HH + xc0, lo);
            split_bits(xr1, &hi, &lo);
            store_short_uc(hb +      (bc * 32 + bl1) * KP + HH + xc1, hi);
            store_short_uc(hb + PS + (bc * 32 + bl1) * KP + HH + xc1, lo);
        }
        if (t + 2 < TT && hs == ((t + 2) & 31) && stv) {
            const float2 v = *(const float2*)(X + (t + 2) * XROW + bc * (32 * II) + e0);
            xr0 = v.x; xr1 = v.y;
        }
        if (t + 1 < TT)
            barrier_xcd(bcnt, 32u * (unsigned)(t + 2));
    }
}

extern "C" void kernel_launch(void* const* d_in, const int* in_sizes, int n_in,
                              void* d_out, int out_size, void* d_ws, size_t ws_size,
                              hipStream_t stream) {
    (void)in_sizes; (void)n_in; (void)out_size; (void)ws_size;
    const float* X    = (const float*)d_in[0];
    const float* Wih  = (const float*)d_in[1];
    const float* Whh  = (const float*)d_in[2];
    const float* bih  = (const float*)d_in[3];
    const float* bhh  = (const float*)d_in[4];
    const float* Wout = (const float*)d_in[5];
    const float* bout = (const float*)d_in[6];
    float* Y = (float*)d_out;

    unsigned* bars = (unsigned*)d_ws;                              // [0, 2048)
    __hip_bfloat16* hbuf = (__hip_bfloat16*)((char*)d_ws + 2048);  // 2 buf x 2 plane

    hipMemsetAsync(d_ws, 0, 2048, stream);

    const size_t lds = (size_t)(64 * KPL * 2 * 2) + 2 * PBS * 4 + 16;  // 159760
    hipFuncSetAttribute((const void*)lstm_persist,
                        hipFuncAttributeMaxDynamicSharedMemorySize, (int)lds);

    hipLaunchKernelGGL(lstm_persist, dim3(NBLK), dim3(NTH), lds, stream,
                       X, Wih, Whh, bih, bhh, Wout, bout, Y, hbuf, bars);
}

// Round 9
// 2500.850 us; speedup vs baseline: 2.2353x; 2.2353x over previous
//
#include <hip/hip_runtime.h>
#include <hip/hip_bf16.h>

#define TT 512
#define BB 256
#define II 13
#define HH 512
#define KPL 552             // LDS W row stride (bank spread)
#define NBLK 256
#define NTH 256
#define NKT 17              // K tiles of 32 (K = 544 = 34 slices of 16)
#define NSL 34              // slices per plane
#define PS2 (NSL * 512)     // shorts per (buf,plane,bc) region: 17408
#define GST 18              // gbuf row stride (floats)
#define XROW (BB * II)      // 3328

typedef __attribute__((ext_vector_type(8))) short short8;
typedef __attribute__((ext_vector_type(4))) float floatx4;
typedef __attribute__((ext_vector_type(4))) int intx4;

__device__ inline float sigm(float v) { return 1.f / (1.f + __expf(-v)); }
__device__ inline float tanh_(float v) {
    float e = __expf(-2.f * fabsf(v));
    float t = (1.f - e) / (1.f + e);
    return v < 0.f ? -t : t;
}
__device__ inline void split_bits(float v, unsigned short* hi, unsigned short* lo) {
    __hip_bfloat16 h = __float2bfloat16(v);
    float r = v - __bfloat162float(h);
    __hip_bfloat16 l = __float2bfloat16(r);
    *hi = __builtin_bit_cast(unsigned short, h);
    *lo = __builtin_bit_cast(unsigned short, l);
}

// ---- MALL-direct (uncached) path: sc0 sc1 bypasses vL1 AND L2. The ONLY
// protocol validated on this part (R5 passed; R8's L2-local variant failed).
__device__ inline unsigned poll_mall(const unsigned* p) {
    unsigned v;
    asm volatile("global_load_dword %0, %1, off sc0 sc1\n\ts_waitcnt vmcnt(0)"
                 : "=v"(v) : "v"(p) : "memory");
    return v;
}
__device__ inline void arrive_mall(unsigned* p) {
    asm volatile("global_atomic_add %0, %1, off sc1" :: "v"(p), "v"(1u) : "memory");
}
__device__ inline intx4 load_b128_uc(const void* p) {   // issue only; NO waitcnt
    intx4 v;
    asm volatile("global_load_dwordx4 %0, %1, off sc0 sc1" : "=v"(v) : "v"(p));
    return v;
}
__device__ inline void store_short_uc(void* p, unsigned short v) {
    unsigned vv = v;
    asm volatile("global_store_short %0, %1, off sc0 sc1" :: "v"(p), "v"(vv) : "memory");
}
__device__ inline void store_dword_uc(void* p, unsigned v) {
    asm volatile("global_store_dword %0, %1, off sc0 sc1" :: "v"(p), "v"(v) : "memory");
}
__device__ inline void store_f32_wt(float* p, float v) {
    asm volatile("global_store_dword %0, %1, off sc0 sc1" :: "v"(p), "v"(v) : "memory");
}

// In-XCD barrier, counter at MALL. __syncthreads drains each wave's vmcnt ->
// all sc0sc1 stores are AT the MALL before tid0's arrive. Bounded spin.
__device__ inline void barrier_xcd(unsigned* cnt, unsigned target) {
    __syncthreads();
    if (threadIdx.x == 0) {
        arrive_mall(cnt);
        int guard = 0;
        unsigned v;
        do { v = poll_mall(cnt); } while ((int)(v - target) < 0 && ++guard < (1 << 16));
    }
    __syncthreads();
}

__global__ void __launch_bounds__(NTH, 1)
lstm_persist(const float* __restrict__ X,   const float* __restrict__ Wih,
             const float* __restrict__ Whh, const float* __restrict__ bih,
             const float* __restrict__ bhh, const float* __restrict__ Wout,
             const float* __restrict__ bout, float* __restrict__ Y,
             unsigned short* __restrict__ hbuf, unsigned* __restrict__ bars)
{
    extern __shared__ char smem[];
    __hip_bfloat16* Wshi = (__hip_bfloat16*)smem;       // [64][KPL] hi
    __hip_bfloat16* Wslo = Wshi + 64 * KPL;             // [64][KPL] lo
    float* gbuf = (float*)(Wslo + 64 * KPL);            // [128][GST] gate staging
    int* shint = (int*)(gbuf + 128 * GST);

    const int tid = threadIdx.x;

    // ---- runtime role assignment: bc = physical XCD, hs = rank within XCD.
    if (tid == 0) {
        unsigned x = __builtin_amdgcn_s_getreg(20 | (3 << 11)) & 7u; // HW_REG_XCC_ID
        unsigned r = __hip_atomic_fetch_add(bars + 256 + x * 16, 1u,
                        __ATOMIC_RELAXED, __HIP_MEMORY_SCOPE_AGENT);
        shint[0] = (int)x;
        shint[1] = (int)(r & 31u);
    }
    __syncthreads();
    const int bc = shint[0];
    const int hs = shint[1];
    unsigned* bcnt = bars + bc * 32;

    // Block-major layout: region(buf,plane) = ((buf*2+plane)*8 + bc) * PS2.
    // Within region: [slice sl][row 0..32][col 0..16]; logical k = sl*16+col.
    // Slices 0..31 = h (slice hs is block (bc,hs)'s private output tile);
    // slice 32 = x cols 0..12 + bias-one col 13 + zero 14,15; slice 33 = zero.
    const int regBase = bc * PS2;
#define REGION(buf, plane) (((buf) * 2 + (plane)) * 8 * PS2 + regBase)

    // ---- init: own-slice + (hs==0) shared x/bias slices. MALL-direct. ----
    {
        unsigned* hw = (unsigned*)hbuf;
        // own h-slice = 0 in both bufs, both planes (h0 = 0; buf1 for safety)
        for (int bp = 0; bp < 4; ++bp)
            store_dword_uc(hw + (REGION(bp >> 1, bp & 1) >> 1) + hs * 256 + tid, 0u);
        if (hs == 0) {   // slices 32,33: x0/bias/padding, both bufs+planes
            for (int e = tid; e < 2 * 1024; e += NTH) {
                int buf = e >> 10, off = e & 1023;
                int row = (off >> 4) & 31, col = off & 15;
                unsigned short vh = 0, vl = 0;
                if (off < 512) {           // slice 32
                    if (col == 13) vh = 0x3F80u;                 // bias-one (hi)
                    else if (col < 13 && buf == 0)
                        split_bits(X[(bc * 32 + row) * II + col], &vh, &vl);
                }
                store_short_uc(hbuf + REGION(buf, 0) + 32 * 512 + off, vh);
                store_short_uc(hbuf + REGION(buf, 1) + 32 * 512 + off, vl);
            }
        }
        const float b0 = bout[0];
        for (int i = tid; i < 16 * 32; i += NTH) {   // Y[hs*16..+16)[bc*32..+32)
            int tr = hs * 16 + (i >> 5), cb = bc * 32 + (i & 31);
            store_f32_wt(&Y[tr * BB + cb], b0);
        }
    }
    // ---- W slice -> LDS (hi/lo split), padded stride ----
    for (int n = 0; n < 64; ++n) {
        int gate = n >> 4, hl = n & 15;
        int gr = gate * HH + hs * 16 + hl;   // global gate row (i,f,g,o order)
        for (int k = tid; k < 544; k += NTH) {
            float v;
            if (k < HH)            v = Whh[gr * HH + k];
            else if (k < HH + II)  v = Wih[gr * II + (k - HH)];
            else if (k == HH + II) v = bih[gr] + bhh[gr];
            else                   v = 0.f;
            unsigned short hi, lo; split_bits(v, &hi, &lo);
            Wshi[n * KPL + k] = __builtin_bit_cast(__hip_bfloat16, hi);
            Wslo[n * KPL + k] = __builtin_bit_cast(__hip_bfloat16, lo);
        }
    }
    // ---- x_1 register preload (hs==1 stages x_1 at t=0) ----
    const int e0 = 2 * tid;
    const bool stv = (e0 < 32 * II);
    const int bl0 = e0 / II, xc0 = e0 - bl0 * II;
    const int e1 = e0 + 1;
    const int bl1 = e1 / II, xc1 = e1 - bl1 * II;
    float xr0 = 0.f, xr1 = 0.f;
    if (hs == 1 && stv) {
        const float2 v = *(const float2*)(X + XROW + bc * (32 * II) + e0);
        xr0 = v.x; xr1 = v.y;
    }

    barrier_xcd(bcnt, 32u);   // init done (epoch 1)

    // ---- main recurrence (R5 compute structure; new addressing) ----
    const int lane = tid & 63, wid = tid >> 6;
    const int mt = wid & 1;                 // batch 16-row half
    const int gp = wid >> 1;                // gate pair {2gp, 2gp+1}
    const int r15  = lane & 15;
    const int kgo  = (lane >> 4) * 8;
    const int slb  = kgo >> 4;              // extra slice within 32-wide tile
    const int lanehoff = (mt * 16 + r15) * 16 + (kgo & 8);
    const int brow0 = (gp * 32 + r15) * KPL;
    const int brow1 = brow0 + 16 * KPL;
    float c0 = 0.f, c1 = 0.f;
    const int ebl2 = tid >> 3;              // elementwise row (0..31)
    const int ej   = (tid & 7) * 2;         // elementwise col pair (ej, ej+1)
    const float2 wout2 = *(const float2*)&Wout[hs * 16 + ej];

    for (int t = 0; t < TT; ++t) {
        const int cur = t & 1, nxt = cur ^ 1;
        const unsigned short* Ahi = hbuf + REGION(cur, 0) + lanehoff;
        const unsigned short* Alo = hbuf + REGION(cur, 1) + lanehoff;

        // issue all 34 A-tile loads (MALL-direct, coalesced), one drain
        intx4 ah[NKT], al[NKT];
#pragma unroll
        for (int kt = 0; kt < NKT; ++kt) {
            const int so = (kt * 2 + slb) * 512;
            ah[kt] = load_b128_uc(Ahi + so);
            al[kt] = load_b128_uc(Alo + so);
        }
        asm volatile("s_waitcnt vmcnt(0)" ::: "memory");
        __builtin_amdgcn_sched_barrier(0);   // rule #18: keep MFMAs below waitcnt

        floatx4 aA0 = {0,0,0,0}, aB0 = {0,0,0,0}, aC0 = {0,0,0,0};
        floatx4 aA1 = {0,0,0,0}, aB1 = {0,0,0,0}, aC1 = {0,0,0,0};
#pragma unroll
        for (int kt = 0; kt < NKT; ++kt) {
            const int k0 = kt * 32 + kgo;
            short8 chi = __builtin_bit_cast(short8, ah[kt]);
            short8 clo = __builtin_bit_cast(short8, al[kt]);
            short8 bh0 = *(const short8*)(Wshi + brow0 + k0);
            short8 bv0 = *(const short8*)(Wslo + brow0 + k0);
            short8 bh1 = *(const short8*)(Wshi + brow1 + k0);
            short8 bv1 = *(const short8*)(Wslo + brow1 + k0);
            aA0 = __builtin_amdgcn_mfma_f32_16x16x32_bf16(chi, bh0, aA0, 0, 0, 0);
            aA1 = __builtin_amdgcn_mfma_f32_16x16x32_bf16(chi, bh1, aA1, 0, 0, 0);
            aB0 = __builtin_amdgcn_mfma_f32_16x16x32_bf16(chi, bv0, aB0, 0, 0, 0);
            aB1 = __builtin_amdgcn_mfma_f32_16x16x32_bf16(chi, bv1, aB1, 0, 0, 0);
            aC0 = __builtin_amdgcn_mfma_f32_16x16x32_bf16(clo, bh0, aC0, 0, 0, 0);
            aC1 = __builtin_amdgcn_mfma_f32_16x16x32_bf16(clo, bh1, aC1, 0, 0, 0);
        }
        floatx4 acc0 = aA0 + aB0 + aC0;
        floatx4 acc1 = aA1 + aB1 + aC1;

        {   // stage gates to LDS  (D frag: row=(lane>>4)*4+r, col=lane&15)
            const int b0r = mt * 16 + (lane >> 4) * 4;
            const int g0 = gp * 2;
#pragma unroll
            for (int r = 0; r < 4; ++r) {
                gbuf[((g0    ) * 32 + b0r + r) * GST + r15] = acc0[r];
                gbuf[((g0 + 1) * 32 + b0r + r) * GST + r15] = acc1[r];
            }
        }
        __syncthreads();
        {   // elementwise: thread owns (row=ebl2, cols ej, ej+1)
            const float2 gi = *(const float2*)&gbuf[(0 * 32 + ebl2) * GST + ej];
            const float2 gf = *(const float2*)&gbuf[(1 * 32 + ebl2) * GST + ej];
            const float2 gg = *(const float2*)&gbuf[(2 * 32 + ebl2) * GST + ej];
            const float2 go = *(const float2*)&gbuf[(3 * 32 + ebl2) * GST + ej];

            c0 = sigm(gf.x) * c0 + sigm(gi.x) * tanh_(gg.x);
            float ha = sigm(go.x) * tanh_(c0);
            c1 = sigm(gf.y) * c1 + sigm(gi.y) * tanh_(gg.y);
            float hb = sigm(go.y) * tanh_(c1);

            // coalesced h write: one dword per plane into own slice hs
            unsigned short ha_hi, ha_lo, hb_hi, hb_lo;
            split_bits(ha, &ha_hi, &ha_lo);
            split_bits(hb, &hb_hi, &hb_lo);
            unsigned* hw = (unsigned*)hbuf;
            const int woff = hs * 256 + ebl2 * 8 + (tid & 7);
            store_dword_uc(hw + (REGION(nxt, 0) >> 1) + woff,
                           (unsigned)ha_hi | ((unsigned)hb_hi << 16));
            store_dword_uc(hw + (REGION(nxt, 1) >> 1) + woff,
                           (unsigned)ha_lo | ((unsigned)hb_lo << 16));

            float p = fmaxf(ha, 0.f) * wout2.x + fmaxf(hb, 0.f) * wout2.y;
#pragma unroll
            for (int s = 4; s >= 1; s >>= 1)
                p += __shfl_xor(p, s);
            if ((tid & 7) == 0)
                atomicAdd(&Y[t * BB + bc * 32 + ebl2], p);
        }
        // rotating x-stager: owner of time s stages at t=s-1 from regs
        // preloaded at t=s-2 (HBM latency hidden under a full step)
        if (t + 1 < TT && hs == ((t + 1) & 31) && stv) {
            unsigned short hi, lo;
            split_bits(xr0, &hi, &lo);
            store_short_uc(hbuf + REGION(nxt, 0) + 32 * 512 + bl0 * 16 + xc0, hi);
            store_short_uc(hbuf + REGION(nxt, 1) + 32 * 512 + bl0 * 16 + xc0, lo);
            split_bits(xr1, &hi, &lo);
            store_short_uc(hbuf + REGION(nxt, 0) + 32 * 512 + bl1 * 16 + xc1, hi);
            store_short_uc(hbuf + REGION(nxt, 1) + 32 * 512 + bl1 * 16 + xc1, lo);
        }
        if (t + 2 < TT && hs == ((t + 2) & 31) && stv) {
            const float2 v = *(const float2*)(X + (t + 2) * XROW + bc * (32 * II) + e0);
            xr0 = v.x; xr1 = v.y;
        }
        if (t + 1 < TT)
            barrier_xcd(bcnt, 32u * (unsigned)(t + 2));
    }
}

extern "C" void kernel_launch(void* const* d_in, const int* in_sizes, int n_in,
                              void* d_out, int out_size, void* d_ws, size_t ws_size,
                              hipStream_t stream) {
    (void)in_sizes; (void)n_in; (void)out_size; (void)ws_size;
    const float* X    = (const float*)d_in[0];
    const float* Wih  = (const float*)d_in[1];
    const float* Whh  = (const float*)d_in[2];
    const float* bih  = (const float*)d_in[3];
    const float* bhh  = (const float*)d_in[4];
    const float* Wout = (const float*)d_in[5];
    const float* bout = (const float*)d_in[6];
    float* Y = (float*)d_out;

    unsigned* bars = (unsigned*)d_ws;                                  // [0, 2048)
    unsigned short* hbuf = (unsigned short*)((char*)d_ws + 2048);      // 2x2x8xPS2

    hipMemsetAsync(d_ws, 0, 2048, stream);

    const size_t lds = (size_t)(64 * KPL * 2 * 2) + 128 * GST * 4 + 16;  // 150544
    hipFuncSetAttribute((const void*)lstm_persist,
                        hipFuncAttributeMaxDynamicSharedMemorySize, (int)lds);

    hipLaunchKernelGGL(lstm_persist, dim3(NBLK), dim3(NTH), lds, stream,
                       X, Wih, Whh, bih, bhh, Wout, bout, Y, hbuf, bars);
}

// Round 10
// 2180.141 us; speedup vs baseline: 2.5641x; 1.1471x over previous
//
#include <hip/hip_runtime.h>
#include <hip/hip_bf16.h>

#define TT 512
#define BB 256
#define II 13
#define HH 512
#define NBLK 256
#define NTH 256
#define NKT 17              // K tiles of 32 (K = 544 = 34 slices of 16)
#define NSL 34              // slices per plane
#define PS2 (NSL * 512)     // shorts per (buf,plane,bc) region: 17408
#define GST 18              // gbuf row stride (floats)
#define XROW (BB * II)      // 3328

typedef __attribute__((ext_vector_type(8))) short short8;
typedef __attribute__((ext_vector_type(4))) float floatx4;
typedef __attribute__((ext_vector_type(4))) int intx4;

__device__ inline float sigm(float v) { return 1.f / (1.f + __expf(-v)); }
__device__ inline float tanh_(float v) {
    float e = __expf(-2.f * fabsf(v));
    float t = (1.f - e) / (1.f + e);
    return v < 0.f ? -t : t;
}
__device__ inline void split_bits(float v, unsigned short* hi, unsigned short* lo) {
    __hip_bfloat16 h = __float2bfloat16(v);
    float r = v - __bfloat162float(h);
    __hip_bfloat16 l = __float2bfloat16(r);
    *hi = __builtin_bit_cast(unsigned short, h);
    *lo = __builtin_bit_cast(unsigned short, l);
}

// ---- MALL-direct (uncached) path: sc0 sc1 bypasses vL1 AND L2. The ONLY
// protocol validated on this part (R5/R9 passed; R8's L2-local variant failed).
__device__ inline unsigned poll_mall(const unsigned* p) {
    unsigned v;
    asm volatile("global_load_dword %0, %1, off sc0 sc1\n\ts_waitcnt vmcnt(0)"
                 : "=v"(v) : "v"(p) : "memory");
    return v;
}
__device__ inline void arrive_mall(unsigned* p) {
    asm volatile("global_atomic_add %0, %1, off sc1" :: "v"(p), "v"(1u) : "memory");
}
__device__ inline intx4 load_b128_uc(const void* p) {   // issue only; NO waitcnt
    intx4 v;
    asm volatile("global_load_dwordx4 %0, %1, off sc0 sc1" : "=v"(v) : "v"(p));
    return v;
}
__device__ inline void store_short_uc(void* p, unsigned short v) {
    unsigned vv = v;
    asm volatile("global_store_short %0, %1, off sc0 sc1" :: "v"(p), "v"(vv) : "memory");
}
__device__ inline void store_dword_uc(void* p, unsigned v) {
    asm volatile("global_store_dword %0, %1, off sc0 sc1" :: "v"(p), "v"(v) : "memory");
}
__device__ inline void store_f32_wt(float* p, float v) {
    asm volatile("global_store_dword %0, %1, off sc0 sc1" :: "v"(p), "v"(v) : "memory");
}

// In-XCD barrier, counter at MALL. __syncthreads drains each wave's vmcnt ->
// all sc0sc1 stores are AT the MALL before tid0's arrive. Bounded spin.
__device__ inline void barrier_xcd(unsigned* cnt, unsigned target) {
    __syncthreads();
    if (threadIdx.x == 0) {
        arrive_mall(cnt);
        int guard = 0;
        unsigned v;
        do { v = poll_mall(cnt); } while ((int)(v - target) < 0 && ++guard < (1 << 16));
    }
    __syncthreads();
}

__global__ void __launch_bounds__(NTH, 1)
lstm_persist(const float* __restrict__ X,   const float* __restrict__ Wih,
             const float* __restrict__ Whh, const float* __restrict__ bih,
             const float* __restrict__ bhh, const float* __restrict__ Wout,
             const float* __restrict__ bout, float* __restrict__ Y,
             unsigned short* __restrict__ hbuf, unsigned* __restrict__ bars)
{
    extern __shared__ char smem[];
    // W in MFMA-fragment order: frag(gate 0..3, plane 0..1, kt 0..16) is a
    // contiguous 1KB block; lane l owns bytes [16l, 16l+16). Conflict-free.
    unsigned short* Wf = (unsigned short*)smem;          // 4*2*17*512 shorts
    float* gbuf = (float*)(Wf + 4 * 2 * NKT * 512);      // [128][GST] gates
    int* shint = (int*)(gbuf + 128 * GST);

    const int tid = threadIdx.x;

    // ---- runtime role assignment: bc = physical XCD, hs = rank within XCD.
    if (tid == 0) {
        unsigned x = __builtin_amdgcn_s_getreg(20 | (3 << 11)) & 7u; // HW_REG_XCC_ID
        unsigned r = __hip_atomic_fetch_add(bars + 256 + x * 16, 1u,
                        __ATOMIC_RELAXED, __HIP_MEMORY_SCOPE_AGENT);
        shint[0] = (int)x;
        shint[1] = (int)(r & 31u);
    }
    __syncthreads();
    const int bc = shint[0];
    const int hs = shint[1];
    unsigned* bcnt = bars + bc * 32;

    // Block-major hbuf layout (R9): region(buf,plane) per bc; within region
    // [slice 0..33][row 0..31][col 0..15]; logical k = sl*16+col.
    const int regBase = bc * PS2;
#define REGION(buf, plane) (((buf) * 2 + (plane)) * 8 * PS2 + regBase)

    // ---- init: own-slice + (hs==0) shared x/bias slices. MALL-direct. ----
    {
        unsigned* hw = (unsigned*)hbuf;
        for (int bp = 0; bp < 4; ++bp)
            store_dword_uc(hw + (REGION(bp >> 1, bp & 1) >> 1) + hs * 256 + tid, 0u);
        if (hs == 0) {   // slices 32,33: x0/bias/padding, both bufs+planes
            for (int e = tid; e < 2 * 1024; e += NTH) {
                int buf = e >> 10, off = e & 1023;
                int row = (off >> 4) & 31, col = off & 15;
                unsigned short vh = 0, vl = 0;
                if (off < 512) {           // slice 32
                    if (col == 13) vh = 0x3F80u;                 // bias-one (hi)
                    else if (col < 13 && buf == 0)
                        split_bits(X[(bc * 32 + row) * II + col], &vh, &vl);
                }
                store_short_uc(hbuf + REGION(buf, 0) + 32 * 512 + off, vh);
                store_short_uc(hbuf + REGION(buf, 1) + 32 * 512 + off, vl);
            }
        }
        const float b0 = bout[0];
        for (int i = tid; i < 16 * 32; i += NTH) {   // Y[hs*16..+16)[bc*32..+32)
            int tr = hs * 16 + (i >> 5), cb = bc * 32 + (i & 31);
            store_f32_wt(&Y[tr * BB + cb], b0);
        }
    }
    // ---- W slice -> LDS in fragment order (hi/lo split) ----
    // Element (gate row hl, k) sits in frag(gate,plane,kt= k>>5) at slot
    // (hl + 16*((k&31)>>3))*8 + (k&7)  == lane*8 + j of the MFMA B-fragment.
    for (int n = 0; n < 64; ++n) {
        int gate = n >> 4, hl = n & 15;
        int gr = gate * HH + hs * 16 + hl;   // global gate row (i,f,g,o order)
        for (int k = tid; k < 544; k += NTH) {
            float v;
            if (k < HH)            v = Whh[gr * HH + k];
            else if (k < HH + II)  v = Wih[gr * II + (k - HH)];
            else if (k == HH + II) v = bih[gr] + bhh[gr];
            else                   v = 0.f;
            unsigned short hi, lo; split_bits(v, &hi, &lo);
            const int slot = (hl + 16 * ((k & 31) >> 3)) * 8 + (k & 7);
            Wf[((gate * 2 + 0) * NKT + (k >> 5)) * 512 + slot] = hi;
            Wf[((gate * 2 + 1) * NKT + (k >> 5)) * 512 + slot] = lo;
        }
    }
    // ---- x_1 register preload (hs==1 stages x_1 at t=0) ----
    const int e0 = 2 * tid;
    const bool stv = (e0 < 32 * II);
    const int bl0 = e0 / II, xc0 = e0 - bl0 * II;
    const int e1 = e0 + 1;
    const int bl1 = e1 / II, xc1 = e1 - bl1 * II;
    float xr0 = 0.f, xr1 = 0.f;
    if (hs == 1 && stv) {
        const float2 v = *(const float2*)(X + XROW + bc * (32 * II) + e0);
        xr0 = v.x; xr1 = v.y;
    }

    barrier_xcd(bcnt, 32u);   // init done (epoch 1)

    // ---- main recurrence ----
    const int lane = tid & 63, wid = tid >> 6;
    const int mt = wid & 1;                 // batch 16-row half
    const int gp = wid >> 1;                // gate pair {2gp, 2gp+1}
    const int r15  = lane & 15;
    const int kgo  = (lane >> 4) * 8;
    const int slb  = kgo >> 4;              // extra slice within 32-wide tile
    const int lanehoff = (mt * 16 + r15) * 16 + (kgo & 8);
    const int lane8 = lane * 8;
    // fragment stream bases for this wave's two gates, both planes
    const unsigned short* F0 = Wf + ((4 * gp + 0) * NKT) * 512 + lane8; // g=2gp  hi
    const unsigned short* F1 = Wf + ((4 * gp + 1) * NKT) * 512 + lane8; // g=2gp  lo
    const unsigned short* F2 = Wf + ((4 * gp + 2) * NKT) * 512 + lane8; // g=2gp+1 hi
    const unsigned short* F3 = Wf + ((4 * gp + 3) * NKT) * 512 + lane8; // g=2gp+1 lo
    float c0 = 0.f, c1 = 0.f;
    const int ebl2 = tid >> 3;              // elementwise row (0..31)
    const int ej   = (tid & 7) * 2;         // elementwise col pair (ej, ej+1)
    const float2 wout2 = *(const float2*)&Wout[hs * 16 + ej];

    for (int t = 0; t < TT; ++t) {
        const int cur = t & 1, nxt = cur ^ 1;
        const unsigned short* Ahi = hbuf + REGION(cur, 0) + lanehoff;
        const unsigned short* Alo = hbuf + REGION(cur, 1) + lanehoff;

        // issue all 34 A-tile loads (MALL-direct, coalesced)
        intx4 ah[NKT], al[NKT];
#pragma unroll
        for (int kt = 0; kt < NKT; ++kt) {
            const int so = (kt * 2 + slb) * 512;
            ah[kt] = load_b128_uc(Ahi + so);
            al[kt] = load_b128_uc(Alo + so);
        }
        // W fragment prefetch (kt 0..3, 4-deep rotation) rides the MALL window
        short8 w0[4], w1[4], w2[4], w3[4];
#pragma unroll
        for (int j = 0; j < 4; ++j) {
            w0[j] = *(const short8*)(F0 + j * 512);
            w1[j] = *(const short8*)(F1 + j * 512);
            w2[j] = *(const short8*)(F2 + j * 512);
            w3[j] = *(const short8*)(F3 + j * 512);
        }
        floatx4 aA0 = {0,0,0,0}, aB0 = {0,0,0,0}, aC0 = {0,0,0,0};
        floatx4 aA1 = {0,0,0,0}, aB1 = {0,0,0,0}, aC1 = {0,0,0,0};

        // phase 1: kt 0..7 ready after 16 oldest loads (34 issued -> vmcnt 18)
        asm volatile("s_waitcnt vmcnt(18)" ::: "memory");
        __builtin_amdgcn_sched_barrier(0);   // rule #18
#pragma unroll
        for (int kt = 0; kt < 8; ++kt) {
            short8 bh0 = w0[kt & 3], bv0 = w1[kt & 3];
            short8 bh1 = w2[kt & 3], bv1 = w3[kt & 3];
            if (kt + 4 < NKT) {
                w0[kt & 3] = *(const short8*)(F0 + (kt + 4) * 512);
                w1[kt & 3] = *(const short8*)(F1 + (kt + 4) * 512);
                w2[kt & 3] = *(const short8*)(F2 + (kt + 4) * 512);
                w3[kt & 3] = *(const short8*)(F3 + (kt + 4) * 512);
            }
            short8 chi = __builtin_bit_cast(short8, ah[kt]);
            short8 clo = __builtin_bit_cast(short8, al[kt]);
            aA0 = __builtin_amdgcn_mfma_f32_16x16x32_bf16(chi, bh0, aA0, 0, 0, 0);
            aA1 = __builtin_amdgcn_mfma_f32_16x16x32_bf16(chi, bh1, aA1, 0, 0, 0);
            aB0 = __builtin_amdgcn_mfma_f32_16x16x32_bf16(chi, bv0, aB0, 0, 0, 0);
            aB1 = __builtin_amdgcn_mfma_f32_16x16x32_bf16(chi, bv1, aB1, 0, 0, 0);
            aC0 = __builtin_amdgcn_mfma_f32_16x16x32_bf16(clo, bh0, aC0, 0, 0, 0);
            aC1 = __builtin_amdgcn_mfma_f32_16x16x32_bf16(clo, bh1, aC1, 0, 0, 0);
        }
        // phase 2: remaining loads drained
        asm volatile("s_waitcnt vmcnt(0)" ::: "memory");
        __builtin_amdgcn_sched_barrier(0);
#pragma unroll
        for (int kt = 8; kt < NKT; ++kt) {
            short8 bh0 = w0[kt & 3], bv0 = w1[kt & 3];
            short8 bh1 = w2[kt & 3], bv1 = w3[kt & 3];
            if (kt + 4 < NKT) {
                w0[kt & 3] = *(const short8*)(F0 + (kt + 4) * 512);
                w1[kt & 3] = *(const short8*)(F1 + (kt + 4) * 512);
                w2[kt & 3] = *(const short8*)(F2 + (kt + 4) * 512);
                w3[kt & 3] = *(const short8*)(F3 + (kt + 4) * 512);
            }
            short8 chi = __builtin_bit_cast(short8, ah[kt]);
            short8 clo = __builtin_bit_cast(short8, al[kt]);
            aA0 = __builtin_amdgcn_mfma_f32_16x16x32_bf16(chi, bh0, aA0, 0, 0, 0);
            aA1 = __builtin_amdgcn_mfma_f32_16x16x32_bf16(chi, bh1, aA1, 0, 0, 0);
            aB0 = __builtin_amdgcn_mfma_f32_16x16x32_bf16(chi, bv0, aB0, 0, 0, 0);
            aB1 = __builtin_amdgcn_mfma_f32_16x16x32_bf16(chi, bv1, aB1, 0, 0, 0);
            aC0 = __builtin_amdgcn_mfma_f32_16x16x32_bf16(clo, bh0, aC0, 0, 0, 0);
            aC1 = __builtin_amdgcn_mfma_f32_16x16x32_bf16(clo, bh1, aC1, 0, 0, 0);
        }
        floatx4 acc0 = aA0 + aB0 + aC0;
        floatx4 acc1 = aA1 + aB1 + aC1;

        {   // stage gates to LDS  (D frag: row=(lane>>4)*4+r, col=lane&15)
            const int b0r = mt * 16 + (lane >> 4) * 4;
            const int g0 = gp * 2;
#pragma unroll
            for (int r = 0; r < 4; ++r) {
                gbuf[((g0    ) * 32 + b0r + r) * GST + r15] = acc0[r];
                gbuf[((g0 + 1) * 32 + b0r + r) * GST + r15] = acc1[r];
            }
        }
        __syncthreads();
        {   // elementwise: thread owns (row=ebl2, cols ej, ej+1)
            const float2 gi = *(const float2*)&gbuf[(0 * 32 + ebl2) * GST + ej];
            const float2 gf = *(const float2*)&gbuf[(1 * 32 + ebl2) * GST + ej];
            const float2 gg = *(const float2*)&gbuf[(2 * 32 + ebl2) * GST + ej];
            const float2 go = *(const float2*)&gbuf[(3 * 32 + ebl2) * GST + ej];

            c0 = sigm(gf.x) * c0 + sigm(gi.x) * tanh_(gg.x);
            float ha = sigm(go.x) * tanh_(c0);
            c1 = sigm(gf.y) * c1 + sigm(gi.y) * tanh_(gg.y);
            float hb = sigm(go.y) * tanh_(c1);

            // coalesced h write: one dword per plane into own slice hs
            unsigned short ha_hi, ha_lo, hb_hi, hb_lo;
            split_bits(ha, &ha_hi, &ha_lo);
            split_bits(hb, &hb_hi, &hb_lo);
            unsigned* hw = (unsigned*)hbuf;
            const int woff = hs * 256 + ebl2 * 8 + (tid & 7);
            store_dword_uc(hw + (REGION(nxt, 0) >> 1) + woff,
                           (unsigned)ha_hi | ((unsigned)hb_hi << 16));
            store_dword_uc(hw + (REGION(nxt, 1) >> 1) + woff,
                           (unsigned)ha_lo | ((unsigned)hb_lo << 16));

            float p = fmaxf(ha, 0.f) * wout2.x + fmaxf(hb, 0.f) * wout2.y;
#pragma unroll
            for (int s = 4; s >= 1; s >>= 1)
                p += __shfl_xor(p, s);
            if ((tid & 7) == 0)
                atomicAdd(&Y[t * BB + bc * 32 + ebl2], p);
        }
        // rotating x-stager: owner of time s stages at t=s-1 from regs
        // preloaded at t=s-2 (HBM latency hidden under a full step)
        if (t + 1 < TT && hs == ((t + 1) & 31) && stv) {
            unsigned short hi, lo;
            split_bits(xr0, &hi, &lo);
            store_short_uc(hbuf + REGION(nxt, 0) + 32 * 512 + bl0 * 16 + xc0, hi);
            store_short_uc(hbuf + REGION(nxt, 1) + 32 * 512 + bl0 * 16 + xc0, lo);
            split_bits(xr1, &hi, &lo);
            store_short_uc(hbuf + REGION(nxt, 0) + 32 * 512 + bl1 * 16 + xc1, hi);
            store_short_uc(hbuf + REGION(nxt, 1) + 32 * 512 + bl1 * 16 + xc1, lo);
        }
        if (t + 2 < TT && hs == ((t + 2) & 31) && stv) {
            const float2 v = *(const float2*)(X + (t + 2) * XROW + bc * (32 * II) + e0);
            xr0 = v.x; xr1 = v.y;
        }
        if (t + 1 < TT)
            barrier_xcd(bcnt, 32u * (unsigned)(t + 2));
    }
}

extern "C" void kernel_launch(void* const* d_in, const int* in_sizes, int n_in,
                              void* d_out, int out_size, void* d_ws, size_t ws_size,
                              hipStream_t stream) {
    (void)in_sizes; (void)n_in; (void)out_size; (void)ws_size;
    const float* X    = (const float*)d_in[0];
    const float* Wih  = (const float*)d_in[1];
    const float* Whh  = (const float*)d_in[2];
    const float* bih  = (const float*)d_in[3];
    const float* bhh  = (const float*)d_in[4];
    const float* Wout = (const float*)d_in[5];
    const float* bout = (const float*)d_in[6];
    float* Y = (float*)d_out;

    unsigned* bars = (unsigned*)d_ws;                                  // [0, 2048)
    unsigned short* hbuf = (unsigned short*)((char*)d_ws + 2048);      // 2x2x8xPS2

    hipMemsetAsync(d_ws, 0, 2048, stream);

    const size_t lds = (size_t)(4 * 2 * NKT * 512 * 2) + 128 * GST * 4 + 16;  // 148496
    hipFuncSetAttribute((const void*)lstm_persist,
                        hipFuncAttributeMaxDynamicSharedMemorySize, (int)lds);

    hipLaunchKernelGGL(lstm_persist, dim3(NBLK), dim3(NTH), lds, stream,
                       X, Wih, Whh, bih, bhh, Wout, bout, Y, hbuf, bars);
}